// Round 5
// baseline (56.372 us; speedup 1.0000x reference)
//
#include <hip/hip_runtime.h>

#define DISP_W 1.0f
#define MAT_W  0.1f
#define CD_W   0.5f

typedef _Float16 half8 __attribute__((ext_vector_type(8)));
typedef float f32x16 __attribute__((ext_vector_type(16)));

constexpr int BB = 4;           // batch
constexpr int NN = 8192;        // points per cloud
constexpr int THREADS = 256;    // 4 waves
constexpr int IB = 128;         // A-rows per block
constexpr int JR = 512;         // B-cols per block
constexpr int NIB = NN / IB;    // 64
constexpr int NJB = NN / JR;    // 16
constexpr int NCHUNK = JR / 32; // 16
constexpr int NPTS = 2 * BB * NN;          // 65536 points (2 clouds)
constexpr int GRID = 2 * BB * NIB * NJB;   // 8192

// Verified K=16 MFMA layout (rounds 3/4, absmax 0.0):
//  A: [xh yh zh  xh yh zh  xl yl | zl ch cl 1 1 0 0 0]
//  B: [uxh uyh uzh uxl uyl uzl uxh uyh | uzh 1 1 ch cl 0 0 0]  (u = -2*pos)
// dot = -2 a.b (hi/lo compensated) + ca + cb = |a-b|^2 (~f32 precision).

__global__ __launch_bounds__(256)
void build_frags(const float* __restrict__ pred_disp,
                 const float* __restrict__ target_disp,
                 const float* __restrict__ tmpl,
                 half8* __restrict__ fragA,      // [cloud][b][n][2] (hi,lo)
                 half8* __restrict__ fragBhi,    // [cloud][b][n]
                 half8* __restrict__ fragBlo)
{
    int p = blockIdx.x * 256 + threadIdx.x;     // 0..65535
    int c = p >> 15;
    int b = (p >> 13) & (BB - 1);
    int n = p & (NN - 1);

    const float* dp = (c ? target_disp : pred_disp) + (size_t)b * NN * 3;
    const float* tp = tmpl + (size_t)b * NN * 3;

    int n3 = n * 3;
    float x = tp[n3 + 0] + dp[n3 + 0];
    float y = tp[n3 + 1] + dp[n3 + 1];
    float z = tp[n3 + 2] + dp[n3 + 2];
    float cc = fmaf(x, x, fmaf(y, y, z * z));

    _Float16 xh = (_Float16)x;  _Float16 xl = (_Float16)(x - (float)xh);
    _Float16 yh = (_Float16)y;  _Float16 yl = (_Float16)(y - (float)yh);
    _Float16 zh = (_Float16)z;  _Float16 zl = (_Float16)(z - (float)zh);
    _Float16 ch = (_Float16)cc; _Float16 cl = (_Float16)(cc - (float)ch);

    float ux = -2.0f * x, uy = -2.0f * y, uz = -2.0f * z;
    _Float16 uxh = (_Float16)ux; _Float16 uxl = (_Float16)(ux - (float)uxh);
    _Float16 uyh = (_Float16)uy; _Float16 uyl = (_Float16)(uy - (float)uyh);
    _Float16 uzh = (_Float16)uz; _Float16 uzl = (_Float16)(uz - (float)uzh);

    const _Float16 one  = (_Float16)1.0f;
    const _Float16 zero = (_Float16)0.0f;

    half8 aHi = {xh, yh, zh, xh, yh, zh, xl, yl};
    half8 aLo = {zl, ch, cl, one, one, zero, zero, zero};
    half8 bHi = {uxh, uyh, uzh, uxl, uyl, uzl, uxh, uyh};
    half8 bLo = {uzh, one, one, ch, cl, zero, zero, zero};

    fragA[(size_t)p * 2 + 0] = aHi;
    fragA[(size_t)p * 2 + 1] = aLo;
    fragBhi[p] = bHi;
    fragBlo[p] = bLo;
}

__global__ __launch_bounds__(THREADS, 8)
void chamfer_mfma(const half8* __restrict__ fragA,
                  const half8* __restrict__ fragBhi,
                  const half8* __restrict__ fragBlo,
                  float* __restrict__ rowpart)
{
    int bx = blockIdx.x;
    int jBlk = bx & (NJB - 1);
    int iBlk = (bx >> 4) & (NIB - 1);
    int b    = (bx >> 10) & (BB - 1);
    int dir  = bx >> 12;
    int cA = dir, cB = dir ^ 1;

    __shared__ half8 sBhi[JR];   // 8 KB
    __shared__ half8 sBlo[JR];   // 8 KB

    const int tid  = threadIdx.x;
    const int lane = tid & 63;
    const int w    = tid >> 6;
    const int hi   = lane >> 5;
    const int li   = lane & 31;

    // ---- stage precomputed B fragments (coalesced dwordx4) ----
    size_t pB = ((size_t)cB * BB + b) * NN + jBlk * JR;
    const half8* gHi = fragBhi + pB;
    const half8* gLo = fragBlo + pB;
    #pragma unroll
    for (int t = 0; t < JR / THREADS; ++t) {
        int idx = t * THREADS + tid;
        sBhi[idx] = gHi[idx];
        sBlo[idx] = gLo[idx];
    }

    // ---- A fragment: one dwordx4 per lane ----
    int i = iBlk * IB + w * 32 + li;
    half8 aF = fragA[(((size_t)cA * BB + b) * NN + i) * 2 + hi];

    __syncthreads();

    f32x16 kZero = {0.f,0.f,0.f,0.f, 0.f,0.f,0.f,0.f, 0.f,0.f,0.f,0.f, 0.f,0.f,0.f,0.f};
    const half8* baseB = hi ? sBlo : sBhi;
    float rm[16];
    #pragma unroll
    for (int r = 0; r < 16; ++r) rm[r] = 1.0e30f;

    #pragma unroll 4
    for (int c = 0; c < NCHUNK; ++c) {
        half8 bF = baseB[c * 32 + li];
        f32x16 acc = __builtin_amdgcn_mfma_f32_32x32x16_f16(aF, bF, kZero, 0, 0, 0);
        #pragma unroll
        for (int r = 0; r < 16; ++r) rm[r] = fminf(rm[r], acc[r]);
    }

    // ---- row mins: butterfly across 32 col-lanes (halves independent) ----
    #pragma unroll
    for (int r = 0; r < 16; ++r) {
        float v = rm[r];
        v = fminf(v, __shfl_xor(v, 1, 64));
        v = fminf(v, __shfl_xor(v, 2, 64));
        v = fminf(v, __shfl_xor(v, 4, 64));
        v = fminf(v, __shfl_xor(v, 8, 64));
        v = fminf(v, __shfl_xor(v, 16, 64));
        rm[r] = v;
    }
    // lanes 0 and 32 hold the 32 row-mins; store directly (no barrier)
    if (li == 0) {
        size_t base = ((size_t)(dir * BB + b) * NJB + jBlk) * NN
                    + (size_t)iBlk * IB + w * 32 + 4 * hi;
        #pragma unroll
        for (int r = 0; r < 16; ++r)
            rowpart[base + (r & 3) + 8 * (r >> 2)] = rm[r];
    }
}

__global__ __launch_bounds__(256)
void final_reduce(const float* __restrict__ pred_disp,
                  const float* __restrict__ target_disp,
                  const float* __restrict__ pred_mat,
                  const float* __restrict__ target_mat,
                  const float* __restrict__ rowpart,
                  float* __restrict__ out)
{
    const int NDISP = BB * NN * 3;   // 98304
    const int NROWS = 2 * BB * NN;   // 65536

    int gtid = blockIdx.x * blockDim.x + threadIdx.x;
    int gstride = gridDim.x * blockDim.x;

    float dsum = 0.0f;
    for (int i = gtid; i < NDISP; i += gstride)
        dsum += fabsf(pred_disp[i] - target_disp[i]);

    float msum = 0.0f;
    for (int t = gtid; t < NROWS; t += gstride) {
        int db = t >> 13;            // dir*BB + b
        int i  = t & (NN - 1);
        const float* p = rowpart + (size_t)db * NJB * NN + i;
        float m = 1.0e30f;
        #pragma unroll
        for (int jb = 0; jb < NJB; ++jb)
            m = fminf(m, p[(size_t)jb * NN]);
        msum += fmaxf(m, 0.0f);      // clamp tiny negatives from dot-form
    }

    float acc = dsum * (DISP_W / (float)NDISP)
              + msum * (CD_W / (float)(BB * NN));

    if (gtid < 2 * BB) {
        float d = pred_mat[gtid] - target_mat[gtid];
        acc += d * d * (MAT_W / (float)(2 * BB));
    }

    for (int off = 32; off > 0; off >>= 1)
        acc += __shfl_down(acc, off, 64);

    __shared__ float wsum[4];
    if ((threadIdx.x & 63) == 0) wsum[threadIdx.x >> 6] = acc;
    __syncthreads();
    if (threadIdx.x == 0)
        atomicAdd(out, wsum[0] + wsum[1] + wsum[2] + wsum[3]);
}

extern "C" void kernel_launch(void* const* d_in, const int* in_sizes, int n_in,
                              void* d_out, int out_size, void* d_ws, size_t ws_size,
                              hipStream_t stream) {
    const float* pred_disp   = (const float*)d_in[0];
    const float* pred_mat    = (const float*)d_in[1];
    const float* target_disp = (const float*)d_in[2];
    const float* target_mat  = (const float*)d_in[3];
    const float* tmpl        = (const float*)d_in[4];

    // ws layout (16B-aligned chunks):
    //   fragA   : NPTS*2 half8 = 2 MB
    //   fragBhi : NPTS   half8 = 1 MB
    //   fragBlo : NPTS   half8 = 1 MB
    //   rowpart : 2*BB*NJB*NN floats = 4 MB   (every slot written exactly once)
    half8* fragA   = (half8*)d_ws;
    half8* fragBhi = fragA + (size_t)NPTS * 2;
    half8* fragBlo = fragBhi + NPTS;
    float* rowpart = (float*)(fragBlo + NPTS);
    float* out = (float*)d_out;

    hipMemsetAsync(d_out, 0, sizeof(float), stream);

    build_frags<<<NPTS / 256, 256, 0, stream>>>(pred_disp, target_disp, tmpl,
                                                fragA, fragBhi, fragBlo);
    chamfer_mfma<<<GRID, THREADS, 0, stream>>>(fragA, fragBhi, fragBlo, rowpart);
    final_reduce<<<256, 256, 0, stream>>>(pred_disp, target_disp, pred_mat, target_mat,
                                          rowpart, out);
}

// Round 6
// 46.635 us; speedup vs baseline: 1.2088x; 1.2088x over previous
//
#include <hip/hip_runtime.h>

#define DISP_W 1.0f
#define MAT_W  0.1f
#define CD_W   0.5f

typedef _Float16 half8 __attribute__((ext_vector_type(8)));
typedef float f32x16 __attribute__((ext_vector_type(16)));

constexpr int BB = 4;           // batch
constexpr int NN = 8192;        // points per cloud
constexpr int THREADS = 256;    // 4 waves
constexpr int IB = 256;         // A-rows per block = 4 waves x 64 (2 frags/wave)
constexpr int JR = 1024;        // B-cols per block
constexpr int NIB = NN / IB;    // 32
constexpr int NJB = NN / JR;    // 8
constexpr int NCHUNK = JR / 32; // 32
constexpr int NPTS = 2 * BB * NN;          // 65536
constexpr int GRID = 2 * BB * NIB * NJB;   // 2048

// Verified K=16 MFMA layout (rounds 3-5, absmax 0.0):
//  A: [xh yh zh  xh yh zh  xl yl | zl ch cl 1 1 0 0 0]
//  B: [uxh uyh uzh uxl uyl uzl uxh uyh | uzh 1 1 ch cl 0 0 0]  (u = -2*pos)
// dot = -2 a.b (hi/lo compensated) + ca + cb = |a-b|^2 (~f32 precision).

__global__ __launch_bounds__(256)
void build_frags(const float* __restrict__ pred_disp,
                 const float* __restrict__ target_disp,
                 const float* __restrict__ tmpl,
                 half8* __restrict__ fragA,      // [cloud][b][n][2] (hi,lo)
                 half8* __restrict__ fragBhi,    // [cloud][b][n]
                 half8* __restrict__ fragBlo)
{
    int p = blockIdx.x * 256 + threadIdx.x;     // 0..65535
    int c = p >> 15;
    int b = (p >> 13) & (BB - 1);
    int n = p & (NN - 1);

    const float* dp = (c ? target_disp : pred_disp) + (size_t)b * NN * 3;
    const float* tp = tmpl + (size_t)b * NN * 3;

    int n3 = n * 3;
    float x = tp[n3 + 0] + dp[n3 + 0];
    float y = tp[n3 + 1] + dp[n3 + 1];
    float z = tp[n3 + 2] + dp[n3 + 2];
    float cc = fmaf(x, x, fmaf(y, y, z * z));

    _Float16 xh = (_Float16)x;  _Float16 xl = (_Float16)(x - (float)xh);
    _Float16 yh = (_Float16)y;  _Float16 yl = (_Float16)(y - (float)yh);
    _Float16 zh = (_Float16)z;  _Float16 zl = (_Float16)(z - (float)zh);
    _Float16 ch = (_Float16)cc; _Float16 cl = (_Float16)(cc - (float)ch);

    float ux = -2.0f * x, uy = -2.0f * y, uz = -2.0f * z;
    _Float16 uxh = (_Float16)ux; _Float16 uxl = (_Float16)(ux - (float)uxh);
    _Float16 uyh = (_Float16)uy; _Float16 uyl = (_Float16)(uy - (float)uyh);
    _Float16 uzh = (_Float16)uz; _Float16 uzl = (_Float16)(uz - (float)uzh);

    const _Float16 one  = (_Float16)1.0f;
    const _Float16 zero = (_Float16)0.0f;

    half8 aHi = {xh, yh, zh, xh, yh, zh, xl, yl};
    half8 aLo = {zl, ch, cl, one, one, zero, zero, zero};
    half8 bHi = {uxh, uyh, uzh, uxl, uyl, uzl, uxh, uyh};
    half8 bLo = {uzh, one, one, ch, cl, zero, zero, zero};

    fragA[(size_t)p * 2 + 0] = aHi;
    fragA[(size_t)p * 2 + 1] = aLo;
    fragBhi[p] = bHi;
    fragBlo[p] = bLo;
}

__global__ __launch_bounds__(THREADS, 4)
void chamfer_mfma(const half8* __restrict__ fragA,
                  const half8* __restrict__ fragBhi,
                  const half8* __restrict__ fragBlo,
                  float* __restrict__ rowpart)
{
    int bx = blockIdx.x;
    int jBlk = bx & (NJB - 1);
    int iBlk = (bx >> 3) & (NIB - 1);
    int b    = (bx >> 8) & (BB - 1);
    int dir  = bx >> 10;
    int cA = dir, cB = dir ^ 1;

    __shared__ half8 sBhi[JR];   // 16 KB
    __shared__ half8 sBlo[JR];   // 16 KB

    const int tid  = threadIdx.x;
    const int lane = tid & 63;
    const int w    = tid >> 6;
    const int hi   = lane >> 5;
    const int li   = lane & 31;

    // ---- stage precomputed B fragments (coalesced dwordx4) ----
    size_t pB = ((size_t)cB * BB + b) * NN + jBlk * JR;
    const half8* gHi = fragBhi + pB;
    const half8* gLo = fragBlo + pB;
    #pragma unroll
    for (int t = 0; t < JR / THREADS; ++t) {
        int idx = t * THREADS + tid;
        sBhi[idx] = gHi[idx];
        sBlo[idx] = gLo[idx];
    }

    // ---- two A fragments per wave (rows i0 and i0+32) ----
    int i0 = iBlk * IB + w * 64 + li;
    size_t aBase = ((size_t)cA * BB + b) * NN;
    half8 aF0 = fragA[(aBase + i0) * 2 + hi];
    half8 aF1 = fragA[(aBase + i0 + 32) * 2 + hi];

    __syncthreads();

    f32x16 kZero = {0.f,0.f,0.f,0.f, 0.f,0.f,0.f,0.f, 0.f,0.f,0.f,0.f, 0.f,0.f,0.f,0.f};
    const half8* baseB = hi ? sBlo : sBhi;
    float rm0[16], rm1[16];
    #pragma unroll
    for (int r = 0; r < 16; ++r) { rm0[r] = 1.0e30f; rm1[r] = 1.0e30f; }

    #pragma unroll 2
    for (int c = 0; c < NCHUNK; ++c) {
        half8 bF = baseB[c * 32 + li];
        f32x16 a0 = __builtin_amdgcn_mfma_f32_32x32x16_f16(aF0, bF, kZero, 0, 0, 0);
        f32x16 a1 = __builtin_amdgcn_mfma_f32_32x32x16_f16(aF1, bF, kZero, 0, 0, 0);
        #pragma unroll
        for (int r = 0; r < 16; ++r) {
            rm0[r] = fminf(rm0[r], a0[r]);
            rm1[r] = fminf(rm1[r], a1[r]);
        }
    }

    // ---- row mins: butterfly across 32 col-lanes (both frags in flight) ----
    #pragma unroll
    for (int r = 0; r < 16; ++r) {
        float v0 = rm0[r], v1 = rm1[r];
        v0 = fminf(v0, __shfl_xor(v0, 1, 64));  v1 = fminf(v1, __shfl_xor(v1, 1, 64));
        v0 = fminf(v0, __shfl_xor(v0, 2, 64));  v1 = fminf(v1, __shfl_xor(v1, 2, 64));
        v0 = fminf(v0, __shfl_xor(v0, 4, 64));  v1 = fminf(v1, __shfl_xor(v1, 4, 64));
        v0 = fminf(v0, __shfl_xor(v0, 8, 64));  v1 = fminf(v1, __shfl_xor(v1, 8, 64));
        v0 = fminf(v0, __shfl_xor(v0, 16, 64)); v1 = fminf(v1, __shfl_xor(v1, 16, 64));
        rm0[r] = v0; rm1[r] = v1;
    }
    if (li == 0) {
        size_t base = ((size_t)(dir * BB + b) * NJB + jBlk) * NN
                    + (size_t)iBlk * IB + w * 64 + 4 * hi;
        #pragma unroll
        for (int r = 0; r < 16; ++r) {
            int off = (r & 3) + 8 * (r >> 2);
            rowpart[base + off]      = rm0[r];
            rowpart[base + 32 + off] = rm1[r];
        }
    }
}

__global__ __launch_bounds__(256)
void final_reduce(const float* __restrict__ pred_disp,
                  const float* __restrict__ target_disp,
                  const float* __restrict__ pred_mat,
                  const float* __restrict__ target_mat,
                  const float* __restrict__ rowpart,
                  float* __restrict__ out)
{
    const int NDISP = BB * NN * 3;   // 98304
    const int NROWS = 2 * BB * NN;   // 65536

    int gtid = blockIdx.x * blockDim.x + threadIdx.x;
    int gstride = gridDim.x * blockDim.x;

    float dsum = 0.0f;
    for (int i = gtid; i < NDISP; i += gstride)
        dsum += fabsf(pred_disp[i] - target_disp[i]);

    float msum = 0.0f;
    for (int t = gtid; t < NROWS; t += gstride) {
        int db = t >> 13;            // dir*BB + b
        int i  = t & (NN - 1);
        const float* p = rowpart + (size_t)db * NJB * NN + i;
        float m = 1.0e30f;
        #pragma unroll
        for (int jb = 0; jb < NJB; ++jb)
            m = fminf(m, p[(size_t)jb * NN]);
        msum += fmaxf(m, 0.0f);      // clamp tiny negatives from dot-form
    }

    float acc = dsum * (DISP_W / (float)NDISP)
              + msum * (CD_W / (float)(BB * NN));

    if (gtid < 2 * BB) {
        float d = pred_mat[gtid] - target_mat[gtid];
        acc += d * d * (MAT_W / (float)(2 * BB));
    }

    for (int off = 32; off > 0; off >>= 1)
        acc += __shfl_down(acc, off, 64);

    __shared__ float wsum[4];
    if ((threadIdx.x & 63) == 0) wsum[threadIdx.x >> 6] = acc;
    __syncthreads();
    if (threadIdx.x == 0)
        atomicAdd(out, wsum[0] + wsum[1] + wsum[2] + wsum[3]);
}

extern "C" void kernel_launch(void* const* d_in, const int* in_sizes, int n_in,
                              void* d_out, int out_size, void* d_ws, size_t ws_size,
                              hipStream_t stream) {
    const float* pred_disp   = (const float*)d_in[0];
    const float* pred_mat    = (const float*)d_in[1];
    const float* target_disp = (const float*)d_in[2];
    const float* target_mat  = (const float*)d_in[3];
    const float* tmpl        = (const float*)d_in[4];

    // ws layout:
    //   fragA   : NPTS*2 half8 = 2 MB
    //   fragBhi : NPTS   half8 = 1 MB
    //   fragBlo : NPTS   half8 = 1 MB
    //   rowpart : 2*BB*NJB*NN floats = 2 MB  (every slot written exactly once)
    half8* fragA   = (half8*)d_ws;
    half8* fragBhi = fragA + (size_t)NPTS * 2;
    half8* fragBlo = fragBhi + NPTS;
    float* rowpart = (float*)(fragBlo + NPTS);
    float* out = (float*)d_out;

    hipMemsetAsync(d_out, 0, sizeof(float), stream);

    build_frags<<<NPTS / 256, 256, 0, stream>>>(pred_disp, target_disp, tmpl,
                                                fragA, fragBhi, fragBlo);
    chamfer_mfma<<<GRID, THREADS, 0, stream>>>(fragA, fragBhi, fragBlo, rowpart);
    final_reduce<<<256, 256, 0, stream>>>(pred_disp, target_disp, pred_mat, target_mat,
                                          rowpart, out);
}

// Round 7
// 46.497 us; speedup vs baseline: 1.2124x; 1.0030x over previous
//
#include <hip/hip_runtime.h>

#define DISP_W 1.0f
#define MAT_W  0.1f
#define CD_W   0.5f

typedef _Float16 half8 __attribute__((ext_vector_type(8)));
typedef float f32x16 __attribute__((ext_vector_type(16)));

constexpr int BB = 4;           // batch
constexpr int NN = 8192;        // points per cloud
constexpr int THREADS = 256;    // 4 waves
constexpr int IB = 128;         // A-rows per block = 4 waves x 32
constexpr int JR = 1024;        // B-cols per block
constexpr int NIB = NN / IB;    // 64
constexpr int NJB = NN / JR;    // 8
constexpr int NCHUNK = JR / 32; // 32
constexpr int NPTS = 2 * BB * NN;          // 65536
constexpr int GRID = 2 * BB * NIB * NJB;   // 4096

// Verified K=16 MFMA layout (rounds 3-6, absmax 0.0):
//  A: [xh yh zh  xh yh zh  xl yl | zl ch cl 1 1 0 0 0]
//  B: [uxh uyh uzh uxl uyl uzl uxh uyh | uzh 1 1 ch cl 0 0 0]  (u = -2*pos)
// dot = -2 a.b (hi/lo compensated) + ca + cb = |a-b|^2 (~f32 precision).

__global__ __launch_bounds__(256)
void build_frags(const float* __restrict__ pred_disp,
                 const float* __restrict__ target_disp,
                 const float* __restrict__ tmpl,
                 half8* __restrict__ fragA,      // [cloud][b][n][2] (hi,lo)
                 half8* __restrict__ fragBhi,    // [cloud][b][n]
                 half8* __restrict__ fragBlo)
{
    int p = blockIdx.x * 256 + threadIdx.x;     // 0..65535
    int c = p >> 15;
    int b = (p >> 13) & (BB - 1);
    int n = p & (NN - 1);

    const float* dp = (c ? target_disp : pred_disp) + (size_t)b * NN * 3;
    const float* tp = tmpl + (size_t)b * NN * 3;

    int n3 = n * 3;
    float x = tp[n3 + 0] + dp[n3 + 0];
    float y = tp[n3 + 1] + dp[n3 + 1];
    float z = tp[n3 + 2] + dp[n3 + 2];
    float cc = fmaf(x, x, fmaf(y, y, z * z));

    _Float16 xh = (_Float16)x;  _Float16 xl = (_Float16)(x - (float)xh);
    _Float16 yh = (_Float16)y;  _Float16 yl = (_Float16)(y - (float)yh);
    _Float16 zh = (_Float16)z;  _Float16 zl = (_Float16)(z - (float)zh);
    _Float16 ch = (_Float16)cc; _Float16 cl = (_Float16)(cc - (float)ch);

    float ux = -2.0f * x, uy = -2.0f * y, uz = -2.0f * z;
    _Float16 uxh = (_Float16)ux; _Float16 uxl = (_Float16)(ux - (float)uxh);
    _Float16 uyh = (_Float16)uy; _Float16 uyl = (_Float16)(uy - (float)uyh);
    _Float16 uzh = (_Float16)uz; _Float16 uzl = (_Float16)(uz - (float)uzh);

    const _Float16 one  = (_Float16)1.0f;
    const _Float16 zero = (_Float16)0.0f;

    half8 aHi = {xh, yh, zh, xh, yh, zh, xl, yl};
    half8 aLo = {zl, ch, cl, one, one, zero, zero, zero};
    half8 bHi = {uxh, uyh, uzh, uxl, uyl, uzl, uxh, uyh};
    half8 bLo = {uzh, one, one, ch, cl, zero, zero, zero};

    fragA[(size_t)p * 2 + 0] = aHi;
    fragA[(size_t)p * 2 + 1] = aLo;
    fragBhi[p] = bHi;
    fragBlo[p] = bLo;
}

__global__ __launch_bounds__(THREADS, 4)
void chamfer_mfma(const half8* __restrict__ fragA,
                  const half8* __restrict__ fragBhi,
                  const half8* __restrict__ fragBlo,
                  float* __restrict__ rowpart)
{
    int bx = blockIdx.x;
    int jBlk = bx & (NJB - 1);
    int iBlk = (bx >> 3) & (NIB - 1);
    int b    = (bx >> 9) & (BB - 1);
    int dir  = bx >> 11;
    int cA = dir, cB = dir ^ 1;

    __shared__ half8 sBhi[JR];   // 16 KB
    __shared__ half8 sBlo[JR];   // 16 KB

    const int tid  = threadIdx.x;
    const int lane = tid & 63;
    const int w    = tid >> 6;
    const int hi   = lane >> 5;
    const int li   = lane & 31;

    // ---- stage precomputed B fragments (coalesced dwordx4) ----
    size_t pB = ((size_t)cB * BB + b) * NN + jBlk * JR;
    const half8* gHi = fragBhi + pB;
    const half8* gLo = fragBlo + pB;
    #pragma unroll
    for (int t = 0; t < JR / THREADS; ++t) {
        int idx = t * THREADS + tid;
        sBhi[idx] = gHi[idx];
        sBlo[idx] = gLo[idx];
    }

    // ---- one A fragment per wave (32 rows; lanes l and l+32 share a point) ----
    int i0 = iBlk * IB + w * 32 + li;
    half8 aF = fragA[(((size_t)cA * BB + b) * NN + i0) * 2 + hi];

    __syncthreads();

    f32x16 kZero = {0.f,0.f,0.f,0.f, 0.f,0.f,0.f,0.f, 0.f,0.f,0.f,0.f, 0.f,0.f,0.f,0.f};
    const half8* baseB = hi ? sBlo : sBhi;
    float rm[16];
    #pragma unroll
    for (int r = 0; r < 16; ++r) rm[r] = 1.0e30f;

    // two column-chunks per iteration share aF -> fold both tiles with one
    // v_min3_f32 per accumulator register (8 VALU insts per 32x32 tile)
    #pragma unroll 2
    for (int c = 0; c < NCHUNK / 2; ++c) {
        half8 bF0 = baseB[(2 * c + 0) * 32 + li];
        half8 bF1 = baseB[(2 * c + 1) * 32 + li];
        f32x16 a0 = __builtin_amdgcn_mfma_f32_32x32x16_f16(aF, bF0, kZero, 0, 0, 0);
        f32x16 a1 = __builtin_amdgcn_mfma_f32_32x32x16_f16(aF, bF1, kZero, 0, 0, 0);
        #pragma unroll
        for (int r = 0; r < 16; ++r) {
            float o;
            asm("v_min3_f32 %0, %1, %2, %3"
                : "=v"(o) : "v"(rm[r]), "v"(a0[r]), "v"(a1[r]));
            rm[r] = o;
        }
    }

    // ---- row mins: butterfly across 32 col-lanes (halves independent) ----
    #pragma unroll
    for (int r = 0; r < 16; ++r) {
        float v = rm[r];
        v = fminf(v, __shfl_xor(v, 1, 64));
        v = fminf(v, __shfl_xor(v, 2, 64));
        v = fminf(v, __shfl_xor(v, 4, 64));
        v = fminf(v, __shfl_xor(v, 8, 64));
        v = fminf(v, __shfl_xor(v, 16, 64));
        rm[r] = v;
    }
    // lanes 0 and 32 hold the 32 row-mins; store directly (no barrier)
    if (li == 0) {
        size_t base = ((size_t)(dir * BB + b) * NJB + jBlk) * NN
                    + (size_t)iBlk * IB + w * 32 + 4 * hi;
        #pragma unroll
        for (int r = 0; r < 16; ++r)
            rowpart[base + (r & 3) + 8 * (r >> 2)] = rm[r];
    }
}

__global__ __launch_bounds__(256)
void final_reduce(const float* __restrict__ pred_disp,
                  const float* __restrict__ target_disp,
                  const float* __restrict__ pred_mat,
                  const float* __restrict__ target_mat,
                  const float* __restrict__ rowpart,
                  float* __restrict__ out)
{
    const int NDISP = BB * NN * 3;   // 98304
    const int NROWS = 2 * BB * NN;   // 65536

    int gtid = blockIdx.x * blockDim.x + threadIdx.x;
    int gstride = gridDim.x * blockDim.x;

    float dsum = 0.0f;
    for (int i = gtid; i < NDISP; i += gstride)
        dsum += fabsf(pred_disp[i] - target_disp[i]);

    float msum = 0.0f;
    for (int t = gtid; t < NROWS; t += gstride) {
        int db = t >> 13;            // dir*BB + b
        int i  = t & (NN - 1);
        const float* p = rowpart + (size_t)db * NJB * NN + i;
        float m = 1.0e30f;
        #pragma unroll
        for (int jb = 0; jb < NJB; ++jb)
            m = fminf(m, p[(size_t)jb * NN]);
        msum += fmaxf(m, 0.0f);      // clamp tiny negatives from dot-form
    }

    float acc = dsum * (DISP_W / (float)NDISP)
              + msum * (CD_W / (float)(BB * NN));

    if (gtid < 2 * BB) {
        float d = pred_mat[gtid] - target_mat[gtid];
        acc += d * d * (MAT_W / (float)(2 * BB));
    }

    for (int off = 32; off > 0; off >>= 1)
        acc += __shfl_down(acc, off, 64);

    __shared__ float wsum[4];
    if ((threadIdx.x & 63) == 0) wsum[threadIdx.x >> 6] = acc;
    __syncthreads();
    if (threadIdx.x == 0)
        atomicAdd(out, wsum[0] + wsum[1] + wsum[2] + wsum[3]);
}

extern "C" void kernel_launch(void* const* d_in, const int* in_sizes, int n_in,
                              void* d_out, int out_size, void* d_ws, size_t ws_size,
                              hipStream_t stream) {
    const float* pred_disp   = (const float*)d_in[0];
    const float* pred_mat    = (const float*)d_in[1];
    const float* target_disp = (const float*)d_in[2];
    const float* target_mat  = (const float*)d_in[3];
    const float* tmpl        = (const float*)d_in[4];

    // ws layout:
    //   fragA   : NPTS*2 half8 = 2 MB
    //   fragBhi : NPTS   half8 = 1 MB
    //   fragBlo : NPTS   half8 = 1 MB
    //   rowpart : 2*BB*NJB*NN floats = 2 MB  (every slot written exactly once)
    half8* fragA   = (half8*)d_ws;
    half8* fragBhi = fragA + (size_t)NPTS * 2;
    half8* fragBlo = fragBhi + NPTS;
    float* rowpart = (float*)(fragBlo + NPTS);
    float* out = (float*)d_out;

    hipMemsetAsync(d_out, 0, sizeof(float), stream);

    build_frags<<<NPTS / 256, 256, 0, stream>>>(pred_disp, target_disp, tmpl,
                                                fragA, fragBhi, fragBlo);
    chamfer_mfma<<<GRID, THREADS, 0, stream>>>(fragA, fragBhi, fragBlo, rowpart);
    final_reduce<<<256, 256, 0, stream>>>(pred_disp, target_disp, pred_mat, target_mat,
                                          rowpart, out);
}